// Round 6
// baseline (112.514 us; speedup 1.0000x reference)
//
#include <hip/hip_runtime.h>
#include <hip/hip_fp16.h>
#include <math.h>

#define NEG 0.2f
#define LOG2E 1.4426950408889634f

typedef float f32x4 __attribute__((ext_vector_type(4)));
typedef _Float16 half8 __attribute__((ext_vector_type(8)));

#if __has_builtin(__builtin_amdgcn_exp2f)
#define EXP2F(x) __builtin_amdgcn_exp2f(x)
#else
#define EXP2F(x) exp2f(x)
#endif

__device__ inline uint cvt2(float a, float b) {
  union {
    decltype(__builtin_amdgcn_cvt_pkrtz(0.f, 0.f)) v;
    uint u;
  } x;
  x.v = __builtin_amdgcn_cvt_pkrtz(a, b);
  return x.u;
}

// ---------------- K0: W (f32 [256][512]) -> f16 MFMA B-fragment order ------
// wf[(((h*4+ct)*8+kk)*64+l)*8 + c] = f16(W[kk*32+(l>>4)*8+c][h*64+ct*16+(l&15)])
__global__ __launch_bounds__(256) void wfrag_prep(const float* __restrict__ W,
                                                  ushort* __restrict__ wf) {
  const int h = blockIdx.x, ct = blockIdx.y;
  const int t = threadIdx.x;
#pragma unroll
  for (int s = 0; s < 2; ++s) {
    int slot = t + s * 256;  // (kk,l)
    int l = slot & 63, kk = slot >> 6;
    int col = h * 64 + ct * 16 + (l & 15);
    int k0 = kk * 32 + (l >> 4) * 8;
    uint outv[4];
#pragma unroll
    for (int c = 0; c < 4; ++c) {
      float x0 = W[(size_t)(k0 + 2 * c) * 512 + col];
      float x1 = W[(size_t)(k0 + 2 * c + 1) * 512 + col];
      outv[c] = cvt2(x0, x1);
    }
    *(uint4*)&wf[(((size_t)((h * 4 + ct) * 8 + kk)) * 64 + l) * 8] = *(uint4*)outv;
  }
}

// ---------------- K1: fused edge-pack + MFMA projection + el/er/ermax + mt -
__global__ __launch_bounds__(256, 4) void proj_fused(
    const float* __restrict__ A, const ushort* __restrict__ wf,
    const float* __restrict__ aw, const int* __restrict__ edges,
    uint* __restrict__ epk, ushort* __restrict__ mt, float* __restrict__ el,
    float* __restrict__ er, uint* __restrict__ ermx) {
  __shared__ ushort ct_lds[64][72];  // [d][j_local]
  const int t = threadIdx.x;
  const int wq = t >> 6, l = t & 63;
  // ---- edge pack: this block packs 16384 ints -> 2048 bytes of bitmask ----
  {
    const size_t cid = (size_t)blockIdx.x * 8 + blockIdx.y;
    const int* ep = edges + cid * 16384 + wq * 64 + l;
#pragma unroll 4
    for (int it = 0; it < 64; ++it) {
      int v = ep[it * 256];
      unsigned long long m = __ballot(v != 0);
      if (l == 0)
        *(unsigned long long*)(epk + ((cid * 16384 + (size_t)it * 256 + wq * 64) >> 5)) = m;
    }
  }
  // ---- GEMM: 64 rows x 64 cols (head h), K=256, f16 MFMA ----
  const int i0 = blockIdx.x * 64;
  const int h = blockIdx.y;
  const int b = i0 >> 11, n0 = i0 & 2047, bh = b * 8 + h;
  const int cl = l & 15, hi = l >> 4;
  const float* arow = A + (size_t)(i0 + wq * 16 + cl) * 256 + hi * 8;
  const int4* wfb = (const int4*)wf + (size_t)h * 32 * 64 + l;
  f32x4 acc[4];
#pragma unroll
  for (int ct = 0; ct < 4; ++ct) acc[ct] = (f32x4){0.f, 0.f, 0.f, 0.f};
#pragma unroll
  for (int kk = 0; kk < 8; ++kk) {
    float4 a0 = *(const float4*)(arow + kk * 32);
    float4 a1 = *(const float4*)(arow + kk * 32 + 4);
    union {
      uint u[4];
      half8 v;
    } af;
    af.u[0] = cvt2(a0.x, a0.y);
    af.u[1] = cvt2(a0.z, a0.w);
    af.u[2] = cvt2(a1.x, a1.y);
    af.u[3] = cvt2(a1.z, a1.w);
#pragma unroll
    for (int ct = 0; ct < 4; ++ct) {
      union {
        int4 i;
        half8 v;
      } bf;
      bf.i = wfb[((size_t)ct * 8 + kk) * 64];
      acc[ct] = __builtin_amdgcn_mfma_f32_16x16x32_f16(af.v, bf.v, acc[ct], 0, 0, 0);
    }
  }
  // ---- el/er (rows i = wq*16 + hi*4 + reg, col d = ct*16 + cl) ----
  float alc[4], arc[4];
#pragma unroll
  for (int ct = 0; ct < 4; ++ct) {
    alc[ct] = aw[h * 128 + ct * 16 + cl];
    arc[ct] = aw[h * 128 + 64 + ct * 16 + cl];
  }
  float ermax_loc = -1e30f;
#pragma unroll
  for (int reg = 0; reg < 4; ++reg) {
    float pl = acc[0][reg] * alc[0] + acc[1][reg] * alc[1] + acc[2][reg] * alc[2] +
               acc[3][reg] * alc[3];
    float pr = acc[0][reg] * arc[0] + acc[1][reg] * arc[1] + acc[2][reg] * arc[2] +
               acc[3][reg] * arc[3];
#pragma unroll
    for (int s = 1; s < 16; s <<= 1) {
      pl += __shfl_xor(pl, s);
      pr += __shfl_xor(pr, s);
    }
    if (cl == 0) {
      int n = n0 + wq * 16 + hi * 4 + reg;
      el[(size_t)bh * 2048 + n] = pl;
      er[(size_t)bh * 2048 + n] = pr;
    }
    ermax_loc = fmaxf(ermax_loc, pr);
  }
  ermax_loc = fmaxf(ermax_loc, __shfl_xor(ermax_loc, 16));
  ermax_loc = fmaxf(ermax_loc, __shfl_xor(ermax_loc, 32));
  if (l == 0) {
    uint bits = __float_as_uint(ermax_loc);
    uint key = (bits & 0x80000000u) ? ~bits : (bits | 0x80000000u);
    atomicMax(&ermx[bh], key);
  }
  // ---- mt (fragment-order V^T) via LDS transpose ----
#pragma unroll
  for (int ct = 0; ct < 4; ++ct) {
    ushort4 us;
    us.x = __half_as_ushort(__float2half(acc[ct][0]));
    us.y = __half_as_ushort(__float2half(acc[ct][1]));
    us.z = __half_as_ushort(__float2half(acc[ct][2]));
    us.w = __half_as_ushort(__float2half(acc[ct][3]));
    *(ushort4*)&ct_lds[ct * 16 + cl][wq * 16 + hi * 4] = us;
  }
  __syncthreads();
  {
    const int f = t >> 5, s = t & 31;
    const int g = f >> 2, nt = f & 3;
    const int r = nt * 16 + (s & 15);
    const int cm = g * 32 + (s >> 4) * 8;
    int4 v0 = *(const int4*)&ct_lds[r][cm];
    int4 v1 = *(const int4*)&ct_lds[r][cm + 16];
    const size_t base = ((size_t)bh * 32 + (n0 >> 6)) * 4096 + f * 512;
    *(int4*)&mt[base + s * 8] = v0;
    *(int4*)&mt[base + (s + 32) * 8] = v1;
  }
}

// ---------------- K2: fused masked softmax + PV via MFMA -------------------
__global__ __launch_bounds__(512, 8) void gat_attn(const ushort* __restrict__ mt,
                                                   const uint* __restrict__ epk,
                                                   const float* __restrict__ el,
                                                   const float* __restrict__ er,
                                                   const uint* __restrict__ ermx,
                                                   float* __restrict__ out) {
  __shared__ __align__(16) char smem[40960];  // vt 32KB dbuf + er_s 8KB
  int4* vt4 = (int4*)smem;
  float* er_s = (float*)(smem + 32768);
  const int t = threadIdx.x;
  const int l = t & 63;
  const int hf = t >> 8;
  const int th = t & 255;
  const int wq = (t >> 6) & 3;
  const int r16 = l & 15, hi = l >> 4;
  const int sh8 = hi * 8;
  const int i0 = blockIdx.x * 64;
  const int h = blockIdx.y, b = blockIdx.z;
  const int bh = b * 8 + h;
  *(float4*)&er_s[t * 4] = *(const float4*)&er[(size_t)bh * 2048 + t * 4];
  const int irow = i0 + wq * 16 + r16;
  const float el_r = el[(size_t)bh * 2048 + irow];
  const uint ky = ermx[bh];
  const float emx = __uint_as_float((ky & 0x80000000u) ? (ky ^ 0x80000000u) : ~ky);
  const float s0 = el_r + emx;
  const float m_r = fmaxf(s0, NEG * s0);  // upper bound of row max score
  const float m2 = m_r * LOG2E;
  const float cA = __builtin_fmaf(el_r, LOG2E, -m2);
  const float cB = __builtin_fmaf(el_r, NEG * LOG2E, -m2);
  const uint* erow = epk + (size_t)(b * 2048 + irow) * 64;
  f32x4 acc[4];
  f32x4 accL = {0.f, 0.f, 0.f, 0.f};
#pragma unroll
  for (int nt = 0; nt < 4; ++nt) acc[nt] = (f32x4){0.f, 0.f, 0.f, 0.f};
  half8 ones;
#pragma unroll
  for (int c = 0; c < 8; ++c) ones[c] = (_Float16)1.f;

  const int jtg0 = hf * 16;
  const int4* srcbase = (const int4*)mt + ((size_t)bh * 32 + jtg0) * 512 + wq * 128 + l;
  // prologue: stage tile 0 into buf 0; preload edge word 0
  unsigned long long ew = *(const unsigned long long*)(erow + jtg0 * 2);
  {
    int4 p0 = srcbase[0];
    int4 p1 = srcbase[64];
    int4* d = vt4 + hf * 512 + wq * 128 + l;
    d[0] = p0;
    d[64] = p1;
  }
  __syncthreads();
  int cur = 0;
  for (int jt = 0; jt < 16; ++jt) {
    int4 nx0, nx1;
    unsigned long long ewn;
    if (jt < 15) {  // issue next-tile loads early (hide under score VALU)
      const int4* s = srcbase + (size_t)(jt + 1) * 512;
      nx0 = s[0];
      nx1 = s[64];
      ewn = *(const unsigned long long*)(erow + (jtg0 + jt + 1) * 2);
    }
    const uint wsh0 = ((uint)ew) >> sh8;
    const uint wsh1 = ((uint)(ew >> 32)) >> sh8;
    const int j0 = (jtg0 + jt) * 64;
    half8 af[2];
#pragma unroll
    for (int g = 0; g < 2; ++g) {
      float4 u0 = *(const float4*)&er_s[j0 + g * 32 + sh8];
      float4 u1 = *(const float4*)&er_s[j0 + g * 32 + sh8 + 4];
      float uv[8] = {u0.x, u0.y, u0.z, u0.w, u1.x, u1.y, u1.z, u1.w};
      const uint wg = g ? wsh1 : wsh0;
      float pv[8];
#pragma unroll
      for (int c = 0; c < 8; ++c) {
        float a = __builtin_fmaf(uv[c], LOG2E, cA);        // (el+u)*log2e - m2
        float bq = __builtin_fmaf(uv[c], NEG * LOG2E, cB);  // 0.2*(el+u)*log2e - m2
        float tt = fmaxf(a, bq);                            // leaky, scaled, <= 0
        float p = EXP2F(tt);
        pv[c] = (wg & (1u << c)) ? p : 0.f;
      }
      union {
        uint u[4];
        half8 v8;
      } fr;
#pragma unroll
      for (int c = 0; c < 4; ++c) fr.u[c] = cvt2(pv[2 * c], pv[2 * c + 1]);
      af[g] = fr.v8;
    }
    const half8* fb = (const half8*)(vt4 + cur * 1024 + hf * 512);
    __builtin_amdgcn_s_setprio(1);
#pragma unroll
    for (int g = 0; g < 2; ++g) {
      accL = __builtin_amdgcn_mfma_f32_16x16x32_f16(af[g], ones, accL, 0, 0, 0);
#pragma unroll
      for (int nt = 0; nt < 4; ++nt) {
        half8 bfr = fb[(g * 4 + nt) * 64 + l];
        acc[nt] = __builtin_amdgcn_mfma_f32_16x16x32_f16(af[g], bfr, acc[nt], 0, 0, 0);
      }
    }
    __builtin_amdgcn_s_setprio(0);
    if (jt < 15) {
      int4* d = vt4 + (cur ^ 1) * 1024 + hf * 512 + wq * 128 + l;
      d[0] = nx0;
      d[64] = nx1;
      ew = ewn;
    }
    __syncthreads();
    cur ^= 1;
  }
  // ---- combine j-halves via LDS (reuses vt region), then epilogue ----
  float* red = (float*)smem;
  if (hf == 1) {
    float* dst = red + th * 21;
#pragma unroll
    for (int nt = 0; nt < 4; ++nt)
#pragma unroll
      for (int k = 0; k < 4; ++k) dst[nt * 4 + k] = acc[nt][k];
#pragma unroll
    for (int k = 0; k < 4; ++k) dst[16 + k] = accL[k];
  }
  __syncthreads();
  if (hf == 0) {
    const float* src = red + th * 21;
#pragma unroll
    for (int reg = 0; reg < 4; ++reg) {
      float Lrow = accL[reg] + src[16 + reg];
      float invL = 1.f / Lrow;
      int orow = i0 + wq * 16 + hi * 4 + reg;
#pragma unroll
      for (int nt = 0; nt < 4; ++nt) {
        float o = (acc[nt][reg] + src[nt * 4 + reg]) * invL;
        float sig = 1.f / (1.f + __expf(-o));
        out[(size_t)(b * 2048 + orow) * 512 + h * 64 + nt * 16 + r16] = sig;
      }
    }
  }
}

extern "C" void kernel_launch(void* const* d_in, const int* in_sizes, int n_in,
                              void* d_out, int out_size, void* d_ws, size_t ws_size,
                              hipStream_t stream) {
  const float* nodes = (const float*)d_in[0];
  const int* edges = (const int*)d_in[1];
  const float* pw = (const float*)d_in[2];
  const float* aw = (const float*)d_in[3];
  float* out = (float*)d_out;

  ushort* mt = (ushort*)d_ws;                          // 8,388,608 B
  float* el = (float*)((char*)d_ws + 8388608);         // 262,144 B
  float* er = (float*)((char*)d_ws + 8650752);         // 262,144 B
  uint* ermx = (uint*)((char*)d_ws + 8912896);         // 128 B
  uint* epk = (uint*)((char*)d_ws + 8913024);          // 2,097,152 B
  ushort* wf = (ushort*)((char*)d_ws + 11010176);      // 262,144 B

  hipMemsetAsync(ermx, 0, 128, stream);  // atomicMax identity (monotone key 0)
  wfrag_prep<<<dim3(8, 4), 256, 0, stream>>>(pw, wf);
  proj_fused<<<dim3(128, 8), 256, 0, stream>>>(nodes, wf, aw, edges, epk, mt, el, er, ermx);
  gat_attn<<<dim3(32, 8, 4), 512, 0, stream>>>(mt, epk, el, er, ermx, out);
}

// Round 7
// 104.888 us; speedup vs baseline: 1.0727x; 1.0727x over previous
//
#include <hip/hip_runtime.h>
#include <hip/hip_fp16.h>
#include <math.h>

#define NEG 0.2f
#define LOG2E 1.4426950408889634f

typedef float f32x4 __attribute__((ext_vector_type(4)));
typedef _Float16 half8 __attribute__((ext_vector_type(8)));

#if __has_builtin(__builtin_amdgcn_exp2f)
#define EXP2F(x) __builtin_amdgcn_exp2f(x)
#else
#define EXP2F(x) exp2f(x)
#endif

__device__ inline uint cvt2(float a, float b) {
  union {
    decltype(__builtin_amdgcn_cvt_pkrtz(0.f, 0.f)) v;
    uint u;
  } x;
  x.v = __builtin_amdgcn_cvt_pkrtz(a, b);
  return x.u;
}

// ---------------- K0: W -> f16 B-fragment order, + zero ermx ---------------
__global__ __launch_bounds__(256) void prep_kernel(const float* __restrict__ W,
                                                   ushort* __restrict__ wf,
                                                   uint* __restrict__ ermx) {
  const int bx = blockIdx.x;
  const int t = threadIdx.x;
  if (bx == 32) {
    if (t < 32) ermx[t] = 0u;  // atomicMax identity under monotone key map
    return;
  }
  const int h = bx >> 2, ct = bx & 3;
#pragma unroll
  for (int s = 0; s < 2; ++s) {
    int slot = t + s * 256;  // (kk,l)
    int l = slot & 63, kk = slot >> 6;
    int col = h * 64 + ct * 16 + (l & 15);
    int k0 = kk * 32 + (l >> 4) * 8;
    uint outv[4];
#pragma unroll
    for (int c = 0; c < 4; ++c) {
      float x0 = W[(size_t)(k0 + 2 * c) * 512 + col];
      float x1 = W[(size_t)(k0 + 2 * c + 1) * 512 + col];
      outv[c] = cvt2(x0, x1);
    }
    *(uint4*)&wf[(((size_t)((h * 4 + ct) * 8 + kk)) * 64 + l) * 8] = *(uint4*)outv;
  }
}

// ---------------- K1: pack edges -> bitmask, high-ILP ----------------------
__global__ __launch_bounds__(256) void pack_edges(const int* __restrict__ e,
                                                  unsigned long long* __restrict__ epk64) {
  const int wid = blockIdx.x * 4 + (threadIdx.x >> 6);  // 0..16383
  const int l = threadIdx.x & 63;
  const size_t base = (size_t)wid * 1024;
#pragma unroll
  for (int it = 0; it < 4; ++it) {
    const size_t off = base + it * 256;
    unsigned long long b0 = __ballot(e[off + l] != 0);
    unsigned long long b1 = __ballot(e[off + 64 + l] != 0);
    unsigned long long b2 = __ballot(e[off + 128 + l] != 0);
    unsigned long long b3 = __ballot(e[off + 192 + l] != 0);
    if (l == 0) {
      ulonglong2 p0, p1;
      p0.x = b0;
      p0.y = b1;
      p1.x = b2;
      p1.y = b3;
      *(ulonglong2*)&epk64[off >> 6] = p0;
      *(ulonglong2*)&epk64[(off >> 6) + 2] = p1;
    }
  }
}

// ---------------- K2: MFMA projection + el/er/ermax + fragment-order mt ----
__global__ __launch_bounds__(256, 4) void proj_mfma(
    const float* __restrict__ A, const ushort* __restrict__ wf,
    const float* __restrict__ aw, ushort* __restrict__ mt,
    float* __restrict__ el, float* __restrict__ er, uint* __restrict__ ermx) {
  __shared__ ushort ct_lds[64][72];  // [d][j_local]
  const int t = threadIdx.x;
  const int wq = t >> 6, l = t & 63;
  const int i0 = blockIdx.x * 64;
  const int h = blockIdx.y;
  const int b = i0 >> 11, n0 = i0 & 2047, bh = b * 8 + h;
  const int cl = l & 15, hi = l >> 4;
  const float* arow = A + (size_t)(i0 + wq * 16 + cl) * 256 + hi * 8;
  const int4* wfb = (const int4*)wf + (size_t)h * 32 * 64 + l;
  f32x4 acc[4];
#pragma unroll
  for (int ct = 0; ct < 4; ++ct) acc[ct] = (f32x4){0.f, 0.f, 0.f, 0.f};
#pragma unroll
  for (int kk = 0; kk < 8; ++kk) {
    float4 a0 = *(const float4*)(arow + kk * 32);
    float4 a1 = *(const float4*)(arow + kk * 32 + 4);
    union {
      uint u[4];
      half8 v;
    } af;
    af.u[0] = cvt2(a0.x, a0.y);
    af.u[1] = cvt2(a0.z, a0.w);
    af.u[2] = cvt2(a1.x, a1.y);
    af.u[3] = cvt2(a1.z, a1.w);
#pragma unroll
    for (int ct = 0; ct < 4; ++ct) {
      union {
        int4 i;
        half8 v;
      } bf;
      bf.i = wfb[((size_t)ct * 8 + kk) * 64];
      acc[ct] = __builtin_amdgcn_mfma_f32_16x16x32_f16(af.v, bf.v, acc[ct], 0, 0, 0);
    }
  }
  // ---- el/er (rows i = wq*16 + hi*4 + reg, col d = ct*16 + cl) ----
  float alc[4], arc[4];
#pragma unroll
  for (int ct = 0; ct < 4; ++ct) {
    alc[ct] = aw[h * 128 + ct * 16 + cl];
    arc[ct] = aw[h * 128 + 64 + ct * 16 + cl];
  }
  float ermax_loc = -1e30f;
#pragma unroll
  for (int reg = 0; reg < 4; ++reg) {
    float pl = acc[0][reg] * alc[0] + acc[1][reg] * alc[1] + acc[2][reg] * alc[2] +
               acc[3][reg] * alc[3];
    float pr = acc[0][reg] * arc[0] + acc[1][reg] * arc[1] + acc[2][reg] * arc[2] +
               acc[3][reg] * arc[3];
#pragma unroll
    for (int s = 1; s < 16; s <<= 1) {
      pl += __shfl_xor(pl, s);
      pr += __shfl_xor(pr, s);
    }
    if (cl == 0) {
      int n = n0 + wq * 16 + hi * 4 + reg;
      el[(size_t)bh * 2048 + n] = pl;
      er[(size_t)bh * 2048 + n] = pr;
    }
    ermax_loc = fmaxf(ermax_loc, pr);
  }
  ermax_loc = fmaxf(ermax_loc, __shfl_xor(ermax_loc, 16));
  ermax_loc = fmaxf(ermax_loc, __shfl_xor(ermax_loc, 32));
  if (l == 0) {
    uint bits = __float_as_uint(ermax_loc);
    uint key = (bits & 0x80000000u) ? ~bits : (bits | 0x80000000u);
    atomicMax(&ermx[bh], key);
  }
  // ---- mt (fragment-order V^T) via LDS transpose ----
#pragma unroll
  for (int ct = 0; ct < 4; ++ct) {
    ushort4 us;
    us.x = __half_as_ushort(__float2half(acc[ct][0]));
    us.y = __half_as_ushort(__float2half(acc[ct][1]));
    us.z = __half_as_ushort(__float2half(acc[ct][2]));
    us.w = __half_as_ushort(__float2half(acc[ct][3]));
    *(ushort4*)&ct_lds[ct * 16 + cl][wq * 16 + hi * 4] = us;
  }
  __syncthreads();
  {
    const int f = t >> 5, s = t & 31;
    const int g = f >> 2, nt = f & 3;
    const int r = nt * 16 + (s & 15);
    const int cm = g * 32 + (s >> 4) * 8;
    int4 v0 = *(const int4*)&ct_lds[r][cm];
    int4 v1 = *(const int4*)&ct_lds[r][cm + 16];
    const size_t base = ((size_t)bh * 32 + (n0 >> 6)) * 4096 + f * 512;
    *(int4*)&mt[base + s * 8] = v0;
    *(int4*)&mt[base + (s + 32) * 8] = v1;
  }
}

// ---------------- K3: fused masked softmax + PV via MFMA -------------------
__global__ __launch_bounds__(512, 8) void gat_attn(const ushort* __restrict__ mt,
                                                   const uint* __restrict__ epk,
                                                   const float* __restrict__ el,
                                                   const float* __restrict__ er,
                                                   const uint* __restrict__ ermx,
                                                   float* __restrict__ out) {
  __shared__ __align__(16) char smem[40960];  // vt 32KB dbuf + er_s 8KB
  int4* vt4 = (int4*)smem;
  float* er_s = (float*)(smem + 32768);
  const int t = threadIdx.x;
  const int l = t & 63;
  const int hf = t >> 8;
  const int th = t & 255;
  const int wq = (t >> 6) & 3;
  const int r16 = l & 15, hi = l >> 4;
  const int sh8 = hi * 8;
  const int i0 = blockIdx.x * 64;
  const int h = blockIdx.y, b = blockIdx.z;
  const int bh = b * 8 + h;
  *(float4*)&er_s[t * 4] = *(const float4*)&er[(size_t)bh * 2048 + t * 4];
  const int irow = i0 + wq * 16 + r16;
  const float el_r = el[(size_t)bh * 2048 + irow];
  const uint ky = ermx[bh];
  const float emx = __uint_as_float((ky & 0x80000000u) ? (ky ^ 0x80000000u) : ~ky);
  const float s0 = el_r + emx;
  const float m_r = fmaxf(s0, NEG * s0);  // upper bound of row max score
  const float m2 = m_r * LOG2E;
  const float cA = __builtin_fmaf(el_r, LOG2E, -m2);
  const float cB = __builtin_fmaf(el_r, NEG * LOG2E, -m2);
  const uint* erow = epk + (size_t)(b * 2048 + irow) * 64;
  f32x4 acc[4];
  f32x4 accL = {0.f, 0.f, 0.f, 0.f};
#pragma unroll
  for (int nt = 0; nt < 4; ++nt) acc[nt] = (f32x4){0.f, 0.f, 0.f, 0.f};
  half8 ones;
#pragma unroll
  for (int c = 0; c < 8; ++c) ones[c] = (_Float16)1.f;

  const int jtg0 = hf * 16;
  const int4* srcbase = (const int4*)mt + ((size_t)bh * 32 + jtg0) * 512 + wq * 128 + l;
  // prologue: stage tile 0 into buf 0; preload edge word 0
  unsigned long long ew = *(const unsigned long long*)(erow + jtg0 * 2);
  {
    int4 p0 = srcbase[0];
    int4 p1 = srcbase[64];
    int4* d = vt4 + hf * 512 + wq * 128 + l;
    d[0] = p0;
    d[64] = p1;
  }
  __syncthreads();
  int cur = 0;
  for (int jt = 0; jt < 16; ++jt) {
    int4 nx0, nx1;
    unsigned long long ewn;
    if (jt < 15) {  // issue next-tile loads early (hide under score VALU)
      const int4* s = srcbase + (size_t)(jt + 1) * 512;
      nx0 = s[0];
      nx1 = s[64];
      ewn = *(const unsigned long long*)(erow + (jtg0 + jt + 1) * 2);
    }
    const uint wsh0 = ((uint)ew) >> sh8;
    const uint wsh1 = ((uint)(ew >> 32)) >> sh8;
    const int j0 = (jtg0 + jt) * 64;
    half8 af[2];
#pragma unroll
    for (int g = 0; g < 2; ++g) {
      float4 u0 = *(const float4*)&er_s[j0 + g * 32 + sh8];
      float4 u1 = *(const float4*)&er_s[j0 + g * 32 + sh8 + 4];
      float uv[8] = {u0.x, u0.y, u0.z, u0.w, u1.x, u1.y, u1.z, u1.w};
      const uint wg = g ? wsh1 : wsh0;
      float pv[8];
#pragma unroll
      for (int c = 0; c < 8; ++c) {
        float a = __builtin_fmaf(uv[c], LOG2E, cA);         // (el+u)*log2e - m2
        float bq = __builtin_fmaf(uv[c], NEG * LOG2E, cB);  // 0.2*(el+u)*log2e - m2
        float tt = fmaxf(a, bq);                            // leaky, scaled, <= 0
        float p = EXP2F(tt);
        pv[c] = (wg & (1u << c)) ? p : 0.f;
      }
      union {
        uint u[4];
        half8 v8;
      } fr;
#pragma unroll
      for (int c = 0; c < 4; ++c) fr.u[c] = cvt2(pv[2 * c], pv[2 * c + 1]);
      af[g] = fr.v8;
    }
    const half8* fb = (const half8*)(vt4 + cur * 1024 + hf * 512);
    __builtin_amdgcn_s_setprio(1);
#pragma unroll
    for (int g = 0; g < 2; ++g) {
      accL = __builtin_amdgcn_mfma_f32_16x16x32_f16(af[g], ones, accL, 0, 0, 0);
#pragma unroll
      for (int nt = 0; nt < 4; ++nt) {
        half8 bfr = fb[(g * 4 + nt) * 64 + l];
        acc[nt] = __builtin_amdgcn_mfma_f32_16x16x32_f16(af[g], bfr, acc[nt], 0, 0, 0);
      }
    }
    __builtin_amdgcn_s_setprio(0);
    if (jt < 15) {
      int4* d = vt4 + (cur ^ 1) * 1024 + hf * 512 + wq * 128 + l;
      d[0] = nx0;
      d[64] = nx1;
      ew = ewn;
    }
    __syncthreads();
    cur ^= 1;
  }
  // ---- combine j-halves via LDS (reuses vt region), then epilogue ----
  float* red = (float*)smem;
  if (hf == 1) {
    float* dst = red + th * 21;
#pragma unroll
    for (int nt = 0; nt < 4; ++nt)
#pragma unroll
      for (int k = 0; k < 4; ++k) dst[nt * 4 + k] = acc[nt][k];
#pragma unroll
    for (int k = 0; k < 4; ++k) dst[16 + k] = accL[k];
  }
  __syncthreads();
  if (hf == 0) {
    const float* src = red + th * 21;
#pragma unroll
    for (int reg = 0; reg < 4; ++reg) {
      float Lrow = accL[reg] + src[16 + reg];
      float invL = 1.f / Lrow;
      int orow = i0 + wq * 16 + hi * 4 + reg;
#pragma unroll
      for (int nt = 0; nt < 4; ++nt) {
        float o = (acc[nt][reg] + src[nt * 4 + reg]) * invL;
        float sig = 1.f / (1.f + __expf(-o));
        out[(size_t)(b * 2048 + orow) * 512 + h * 64 + nt * 16 + r16] = sig;
      }
    }
  }
}

extern "C" void kernel_launch(void* const* d_in, const int* in_sizes, int n_in,
                              void* d_out, int out_size, void* d_ws, size_t ws_size,
                              hipStream_t stream) {
  const float* nodes = (const float*)d_in[0];
  const int* edges = (const int*)d_in[1];
  const float* pw = (const float*)d_in[2];
  const float* aw = (const float*)d_in[3];
  float* out = (float*)d_out;

  ushort* mt = (ushort*)d_ws;                          // 8,388,608 B
  float* el = (float*)((char*)d_ws + 8388608);         // 262,144 B
  float* er = (float*)((char*)d_ws + 8650752);         // 262,144 B
  uint* ermx = (uint*)((char*)d_ws + 8912896);         // 128 B
  uint* epk = (uint*)((char*)d_ws + 8913024);          // 2,097,152 B
  ushort* wf = (ushort*)((char*)d_ws + 11010176);      // 262,144 B

  prep_kernel<<<33, 256, 0, stream>>>(pw, (ushort*)wf, ermx);
  pack_edges<<<4096, 256, 0, stream>>>(edges, (unsigned long long*)epk);
  proj_mfma<<<dim3(128, 8), 256, 0, stream>>>(nodes, wf, aw, mt, el, er, ermx);
  gat_attn<<<dim3(32, 8, 4), 512, 0, stream>>>(mt, epk, el, er, ermx, out);
}

// Round 9
// 91.335 us; speedup vs baseline: 1.2319x; 1.1484x over previous
//
#include <hip/hip_runtime.h>
#include <hip/hip_fp16.h>
#include <math.h>

#define NEG 0.2f
#define LOG2E 1.4426950408889634f

typedef float f32x4 __attribute__((ext_vector_type(4)));
typedef _Float16 half8 __attribute__((ext_vector_type(8)));
typedef _Float16 h2v __attribute__((ext_vector_type(2)));

extern "C" __device__ _Float16 __ocml_exp2_f16(_Float16);

__device__ inline uint cvt2(float a, float b) {
  union {
    decltype(__builtin_amdgcn_cvt_pkrtz(0.f, 0.f)) v;
    uint u;
  } x;
  x.v = __builtin_amdgcn_cvt_pkrtz(a, b);
  return x.u;
}

__device__ inline h2v u2h(uint u) {
  union {
    uint u;
    h2v v;
  } x;
  x.u = u;
  return x.v;
}

__device__ inline uint h2u(h2v v) {
  union {
    uint u;
    h2v v;
  } x;
  x.v = v;
  return x.u;
}

// ---------------- K0: W -> f16 B-fragment order, + zero ermx ---------------
__global__ __launch_bounds__(256) void prep_kernel(const float* __restrict__ W,
                                                   ushort* __restrict__ wf,
                                                   uint* __restrict__ ermx) {
  const int bx = blockIdx.x;
  const int t = threadIdx.x;
  if (bx == 32) {
    if (t < 32) ermx[t] = 0u;  // atomicMax identity under monotone key map
    return;
  }
  const int h = bx >> 2, ct = bx & 3;
#pragma unroll
  for (int s = 0; s < 2; ++s) {
    int slot = t + s * 256;  // (kk,l)
    int l = slot & 63, kk = slot >> 6;
    int col = h * 64 + ct * 16 + (l & 15);
    int k0 = kk * 32 + (l >> 4) * 8;
    uint outv[4];
#pragma unroll
    for (int c = 0; c < 4; ++c) {
      float x0 = W[(size_t)(k0 + 2 * c) * 512 + col];
      float x1 = W[(size_t)(k0 + 2 * c + 1) * 512 + col];
      outv[c] = cvt2(x0, x1);
    }
    *(uint4*)&wf[(((size_t)((h * 4 + ct) * 8 + kk)) * 64 + l) * 8] = *(uint4*)outv;
  }
}

// ---------------- K1: heterogeneous pack(4/5) + MFMA-proj(1/5) -------------
__global__ __launch_bounds__(256, 4) void pack_proj(
    const int* __restrict__ e, unsigned long long* __restrict__ epk64,
    const float* __restrict__ A, const ushort* __restrict__ wf,
    const float* __restrict__ aw, ushort* __restrict__ mt,
    float* __restrict__ el, float* __restrict__ er, uint* __restrict__ ermx) {
  __shared__ ushort ct_lds[64][72];
  const int bx = blockIdx.x;
  const int t = threadIdx.x;
  const int l = t & 63;
  if (bx % 5 != 4) {
    // ---- edge pack block ----
    const int pack_id = (bx / 5) * 4 + (bx % 5);
    const int wid = pack_id * 4 + (t >> 6);  // 0..16383
    const size_t base = (size_t)wid * 1024;
#pragma unroll
    for (int it = 0; it < 4; ++it) {
      const size_t off = base + it * 256;
      unsigned long long b0 = __ballot(e[off + l] != 0);
      unsigned long long b1 = __ballot(e[off + 64 + l] != 0);
      unsigned long long b2 = __ballot(e[off + 128 + l] != 0);
      unsigned long long b3 = __ballot(e[off + 192 + l] != 0);
      if (l == 0) {
        ulonglong2 p0, p1;
        p0.x = b0;
        p0.y = b1;
        p1.x = b2;
        p1.y = b3;
        *(ulonglong2*)&epk64[off >> 6] = p0;
        *(ulonglong2*)&epk64[(off >> 6) + 2] = p1;
      }
    }
    return;
  }
  // ---- projection block ----
  const int pid = bx / 5;
  const int wq = t >> 6;
  const int i0 = (pid & 127) * 64;
  const int h = pid >> 7;
  const int b = i0 >> 11, n0 = i0 & 2047, bh = b * 8 + h;
  const int cl = l & 15, hi = l >> 4;
  const float* arow = A + (size_t)(i0 + wq * 16 + cl) * 256 + hi * 8;
  const int4* wfb = (const int4*)wf + (size_t)h * 32 * 64 + l;
  f32x4 acc[4];
#pragma unroll
  for (int ct = 0; ct < 4; ++ct) acc[ct] = (f32x4){0.f, 0.f, 0.f, 0.f};
#pragma unroll
  for (int kk = 0; kk < 8; ++kk) {
    float4 a0 = *(const float4*)(arow + kk * 32);
    float4 a1 = *(const float4*)(arow + kk * 32 + 4);
    union {
      uint u[4];
      half8 v;
    } af;
    af.u[0] = cvt2(a0.x, a0.y);
    af.u[1] = cvt2(a0.z, a0.w);
    af.u[2] = cvt2(a1.x, a1.y);
    af.u[3] = cvt2(a1.z, a1.w);
#pragma unroll
    for (int ct = 0; ct < 4; ++ct) {
      union {
        int4 i;
        half8 v;
      } bf;
      bf.i = wfb[((size_t)ct * 8 + kk) * 64];
      acc[ct] = __builtin_amdgcn_mfma_f32_16x16x32_f16(af.v, bf.v, acc[ct], 0, 0, 0);
    }
  }
  float alc[4], arc[4];
#pragma unroll
  for (int ct = 0; ct < 4; ++ct) {
    alc[ct] = aw[h * 128 + ct * 16 + cl];
    arc[ct] = aw[h * 128 + 64 + ct * 16 + cl];
  }
  float ermax_loc = -1e30f;
#pragma unroll
  for (int reg = 0; reg < 4; ++reg) {
    float pl = acc[0][reg] * alc[0] + acc[1][reg] * alc[1] + acc[2][reg] * alc[2] +
               acc[3][reg] * alc[3];
    float pr = acc[0][reg] * arc[0] + acc[1][reg] * arc[1] + acc[2][reg] * arc[2] +
               acc[3][reg] * arc[3];
#pragma unroll
    for (int s = 1; s < 16; s <<= 1) {
      pl += __shfl_xor(pl, s);
      pr += __shfl_xor(pr, s);
    }
    if (cl == 0) {
      int n = n0 + wq * 16 + hi * 4 + reg;
      el[(size_t)bh * 2048 + n] = pl;
      er[(size_t)bh * 2048 + n] = pr;
    }
    ermax_loc = fmaxf(ermax_loc, pr);
  }
  ermax_loc = fmaxf(ermax_loc, __shfl_xor(ermax_loc, 16));
  ermax_loc = fmaxf(ermax_loc, __shfl_xor(ermax_loc, 32));
  if (l == 0) {
    uint bits = __float_as_uint(ermax_loc);
    uint key = (bits & 0x80000000u) ? ~bits : (bits | 0x80000000u);
    atomicMax(&ermx[bh], key);
  }
#pragma unroll
  for (int ct = 0; ct < 4; ++ct) {
    ushort4 us;
    us.x = __half_as_ushort(__float2half(acc[ct][0]));
    us.y = __half_as_ushort(__float2half(acc[ct][1]));
    us.z = __half_as_ushort(__float2half(acc[ct][2]));
    us.w = __half_as_ushort(__float2half(acc[ct][3]));
    *(ushort4*)&ct_lds[ct * 16 + cl][wq * 16 + hi * 4] = us;
  }
  __syncthreads();
  {
    const int f = t >> 5, s = t & 31;
    const int g = f >> 2, nt = f & 3;
    const int r = nt * 16 + (s & 15);
    const int cm = g * 32 + (s >> 4) * 8;
    int4 v0 = *(const int4*)&ct_lds[r][cm];
    int4 v1 = *(const int4*)&ct_lds[r][cm + 16];
    const size_t base = ((size_t)bh * 32 + (n0 >> 6)) * 4096 + f * 512;
    *(int4*)&mt[base + s * 8] = v0;
    *(int4*)&mt[base + (s + 32) * 8] = v1;
  }
}

// ---------------- K2: fused masked softmax + PV via MFMA -------------------
__global__ __launch_bounds__(512, 8) void gat_attn(const ushort* __restrict__ mt,
                                                   const uint* __restrict__ epk,
                                                   const float* __restrict__ el,
                                                   const float* __restrict__ er,
                                                   const uint* __restrict__ ermx,
                                                   float* __restrict__ out) {
  __shared__ __align__(16) char smem[36864];  // vt 32KB dbuf + er_sh 4KB (f16)
  int4* vt4 = (int4*)smem;
  uint* ersh = (uint*)(smem + 32768);  // 1024 packed f16 pairs
  const int t = threadIdx.x;
  const int l = t & 63;
  const int hf = t >> 8;
  const int th = t & 255;
  const int wq = (t >> 6) & 3;
  const int r16 = l & 15, hi = l >> 4;
  const int sh8 = hi * 8;
  const int i0 = blockIdx.x * 64;
  const int h = blockIdx.y, b = blockIdx.z;
  const int bh = b * 8 + h;
  if (t < 256) {  // stage er as packed f16 pairs (RTZ)
    float4 e0 = *(const float4*)&er[(size_t)bh * 2048 + t * 8];
    float4 e1 = *(const float4*)&er[(size_t)bh * 2048 + t * 8 + 4];
    uint4 pk;
    pk.x = cvt2(e0.x, e0.y);
    pk.y = cvt2(e0.z, e0.w);
    pk.z = cvt2(e1.x, e1.y);
    pk.w = cvt2(e1.z, e1.w);
    *(uint4*)&ersh[t * 4] = pk;
  }
  const int irow = i0 + wq * 16 + r16;
  const float el_r = el[(size_t)bh * 2048 + irow];
  const uint ky = ermx[bh];
  const float emx = __uint_as_float((ky & 0x80000000u) ? (ky ^ 0x80000000u) : ~ky);
  const float s0 = el_r + emx;
  const float m_r = fmaxf(s0, NEG * s0);  // upper bound of row max score
  const float m2 = m_r * LOG2E;
  const float cAf = __builtin_fmaf(el_r, LOG2E, -m2);
  const float cBf = __builtin_fmaf(el_r, NEG * LOG2E, -m2);
  const h2v cA2 = {(_Float16)cAf, (_Float16)cAf};
  const h2v cB2 = {(_Float16)cBf, (_Float16)cBf};
  const h2v l2e2 = {(_Float16)LOG2E, (_Float16)LOG2E};
  const h2v nl2e2 = {(_Float16)(NEG * LOG2E), (_Float16)(NEG * LOG2E)};
  const uint* erow = epk + (size_t)(b * 2048 + irow) * 64;
  f32x4 acc[4];
  f32x4 accL = {0.f, 0.f, 0.f, 0.f};
#pragma unroll
  for (int nt = 0; nt < 4; ++nt) acc[nt] = (f32x4){0.f, 0.f, 0.f, 0.f};
  half8 ones;
#pragma unroll
  for (int c = 0; c < 8; ++c) ones[c] = (_Float16)1.f;

  const int jtg0 = hf * 16;
  const int4* srcbase = (const int4*)mt + ((size_t)bh * 32 + jtg0) * 512 + wq * 128 + l;
  unsigned long long ew = *(const unsigned long long*)(erow + jtg0 * 2);
  {
    int4 p0 = srcbase[0];
    int4 p1 = srcbase[64];
    int4* d = vt4 + hf * 512 + wq * 128 + l;
    d[0] = p0;
    d[64] = p1;
  }
  __syncthreads();
  int cur = 0;
  for (int jt = 0; jt < 16; ++jt) {
    int4 nx0, nx1;
    unsigned long long ewn;
    if (jt < 15) {  // issue next-tile loads early (hide under score VALU)
      const int4* s = srcbase + (size_t)(jt + 1) * 512;
      nx0 = s[0];
      nx1 = s[64];
      ewn = *(const unsigned long long*)(erow + (jtg0 + jt + 1) * 2);
    }
    const uint wsh0 = ((uint)ew) >> sh8;
    const uint wsh1 = ((uint)(ew >> 32)) >> sh8;
    const int j0 = (jtg0 + jt) * 64;
    half8 af[2];
#pragma unroll
    for (int g = 0; g < 2; ++g) {
      uint4 uv = *(const uint4*)&ersh[(j0 >> 1) + g * 16 + hi * 4];
      uint uvw[4] = {uv.x, uv.y, uv.z, uv.w};
      const uint wg = g ? wsh1 : wsh0;
      union {
        uint u[4];
        half8 v8;
      } fr;
#pragma unroll
      for (int q = 0; q < 4; ++q) {
        h2v u2 = u2h(uvw[q]);
#if __has_builtin(__builtin_elementwise_fma)
        h2v a2 = __builtin_elementwise_fma(u2, l2e2, cA2);
        h2v b2 = __builtin_elementwise_fma(u2, nl2e2, cB2);
#else
        h2v a2 = u2 * l2e2 + cA2;
        h2v b2 = u2 * nl2e2 + cB2;
#endif
        h2v t2 = __builtin_elementwise_max(a2, b2);  // leaky, scaled, <= ~0
        h2v p2;
        p2[0] = __ocml_exp2_f16(t2[0]);
        p2[1] = __ocml_exp2_f16(t2[1]);
        uint pu = h2u(p2);
        uint mlo = (uint)(((int)(wg << (31 - 2 * q))) >> 31);
        uint mhi = (uint)(((int)(wg << (30 - 2 * q))) >> 31);
        uint mask2 = (mlo & 0x0000FFFFu) | (mhi & 0xFFFF0000u);
        fr.u[q] = pu & mask2;
      }
      af[g] = fr.v8;
    }
    const half8* fb = (const half8*)(vt4 + cur * 1024 + hf * 512);
    __builtin_amdgcn_s_setprio(1);
#pragma unroll
    for (int g = 0; g < 2; ++g) {
      accL = __builtin_amdgcn_mfma_f32_16x16x32_f16(af[g], ones, accL, 0, 0, 0);
#pragma unroll
      for (int nt = 0; nt < 4; ++nt) {
        half8 bfr = fb[(g * 4 + nt) * 64 + l];
        acc[nt] = __builtin_amdgcn_mfma_f32_16x16x32_f16(af[g], bfr, acc[nt], 0, 0, 0);
      }
    }
    __builtin_amdgcn_s_setprio(0);
    if (jt < 15) {
      int4* d = vt4 + (cur ^ 1) * 1024 + hf * 512 + wq * 128 + l;
      d[0] = nx0;
      d[64] = nx1;
      ew = ewn;
    }
    __syncthreads();
    cur ^= 1;
  }
  // ---- combine j-halves via LDS (reuses vt region), then epilogue ----
  float* red = (float*)smem;
  if (hf == 1) {
    float* dst = red + th * 21;
#pragma unroll
    for (int nt = 0; nt < 4; ++nt)
#pragma unroll
      for (int k = 0; k < 4; ++k) dst[nt * 4 + k] = acc[nt][k];
#pragma unroll
    for (int k = 0; k < 4; ++k) dst[16 + k] = accL[k];
  }
  __syncthreads();
  if (hf == 0) {
    const float* src = red + th * 21;
#pragma unroll
    for (int reg = 0; reg < 4; ++reg) {
      float Lrow = accL[reg] + src[16 + reg];
      float invL = 1.f / Lrow;
      int orow = i0 + wq * 16 + hi * 4 + reg;
#pragma unroll
      for (int nt = 0; nt < 4; ++nt) {
        float o = (acc[nt][reg] + src[nt * 4 + reg]) * invL;
        float sig = 1.f / (1.f + __expf(-o));
        out[(size_t)(b * 2048 + orow) * 512 + h * 64 + nt * 16 + r16] = sig;
      }
    }
  }
}

extern "C" void kernel_launch(void* const* d_in, const int* in_sizes, int n_in,
                              void* d_out, int out_size, void* d_ws, size_t ws_size,
                              hipStream_t stream) {
  const float* nodes = (const float*)d_in[0];
  const int* edges = (const int*)d_in[1];
  const float* pw = (const float*)d_in[2];
  const float* aw = (const float*)d_in[3];
  float* out = (float*)d_out;

  ushort* mt = (ushort*)d_ws;                          // 8,388,608 B
  float* el = (float*)((char*)d_ws + 8388608);         // 262,144 B
  float* er = (float*)((char*)d_ws + 8650752);         // 262,144 B
  uint* ermx = (uint*)((char*)d_ws + 8912896);         // 128 B
  uint* epk = (uint*)((char*)d_ws + 8913024);          // 2,097,152 B
  ushort* wf = (ushort*)((char*)d_ws + 11010176);      // 262,144 B

  prep_kernel<<<33, 256, 0, stream>>>(pw, wf, ermx);
  pack_proj<<<5120, 256, 0, stream>>>(edges, (unsigned long long*)epk, nodes, wf, aw,
                                      mt, el, er, ermx);
  gat_attn<<<dim3(32, 8, 4), 512, 0, stream>>>(mt, epk, el, er, ermx, out);
}